// Round 4
// baseline (175.539 us; speedup 1.0000x reference)
//
#include <hip/hip_runtime.h>

typedef unsigned short u16;
typedef unsigned int u32;
typedef unsigned long long u64;
typedef __attribute__((ext_vector_type(8))) short s16x8;
typedef __attribute__((ext_vector_type(8))) __bf16 bf16x8;
typedef __attribute__((ext_vector_type(4))) float fx4;
typedef __attribute__((ext_vector_type(16))) float fx16;
typedef __attribute__((ext_vector_type(2))) u32 u32x2;
typedef __attribute__((ext_vector_type(4))) u32 u32x4;

// ---------- helpers ----------
__device__ __forceinline__ fx4 mfma_16x16x32(s16x8 a, s16x8 b, fx4 c) {
  return __builtin_amdgcn_mfma_f32_16x16x32_bf16(
      __builtin_bit_cast(bf16x8, a), __builtin_bit_cast(bf16x8, b), c, 0, 0, 0);
}
__device__ __forceinline__ fx16 mfma_32x32x16(s16x8 a, s16x8 b, fx16 c) {
  return __builtin_amdgcn_mfma_f32_32x32x16_bf16(
      __builtin_bit_cast(bf16x8, a), __builtin_bit_cast(bf16x8, b), c, 0, 0, 0);
}

__device__ __forceinline__ u16 f2bf(float f) {
  u32 u = __builtin_bit_cast(u32, f);
  u32 r = u + 0x7fffu + ((u >> 16) & 1u);
  return (u16)(r >> 16);
}
__device__ __forceinline__ float bf2f(u16 h) {
  u32 u = ((u32)h) << 16;
  return __builtin_bit_cast(float, u);
}

__device__ __forceinline__ u32 cvtpk(float lo, float hi) {
  u32 r;
  asm("v_cvt_pk_bf16_f32 %0, %1, %2" : "=v"(r) : "v"(lo), "v"(hi));
  return r;
}

__device__ __forceinline__ float max3f(float a, float b, float c) {
  float r;
  asm("v_max3_f32 %0, %1, %2, %3" : "=v"(r) : "v"(a), "v"(b), "v"(c));
  return r;
}

__device__ __forceinline__ void plswap(u32& x, u32& y) {
  typedef __attribute__((ext_vector_type(2))) unsigned int uix2;
  uix2 r = __builtin_amdgcn_permlane32_swap(x, y, false, false);
  x = r[0];
  y = r[1];
}

__device__ __forceinline__ float xhalf_max(float v) {
  u32 a = __builtin_bit_cast(u32, v), b = a;
  plswap(a, b);
  return fmaxf(__builtin_bit_cast(float, a), __builtin_bit_cast(float, b));
}
__device__ __forceinline__ float xhalf_sum(float v) {
  u32 a = __builtin_bit_cast(u32, v), b = a;
  plswap(a, b);
  return __builtin_bit_cast(float, a) + __builtin_bit_cast(float, b);
}

__device__ __forceinline__ void gload16(const void* g, void* l) {
  __builtin_amdgcn_global_load_lds(
      (const __attribute__((address_space(1))) u32*)g,
      (__attribute__((address_space(3))) u32*)l, 16, 0, 0);
}

// ---------- constants ----------
#define B_ 2
#define T_ 2048
#define C_ 1024
#define H_ 16
#define HD_ 64
#define BH_ 32
#define M_ 4096   // B*T
// (1/sqrt(64)) * log2(e), folded into Q at GEMM1 epilogue (fused RoPE)
#define CF_ 0.18033688011112042f

// ---------- prep kernels ----------
__global__ void rope_table_k(float* __restrict__ ct, float* __restrict__ st) {
  int id = blockIdx.x * 256 + threadIdx.x;  // 65536 = T*32
  int t = id >> 5, i = id & 31;
  float f = exp2f(-(float)i * (13.287712379549449f / 32.0f));
  float a = (float)t * f;
  float s, c;
  sincosf(a, &s, &c);
  ct[id] = c;
  st[id] = s;
}

__global__ void cvt_f32_bf16_k(const float* __restrict__ in, u16* __restrict__ outp) {
  int id = blockIdx.x * 256 + threadIdx.x;
  const fx4* p = (const fx4*)(in + (u64)id * 8);
  fx4 v0 = p[0], v1 = p[1];
  s16x8 r;
#pragma unroll
  for (int j = 0; j < 4; ++j) {
    r[j] = (short)f2bf(v0[j]);
    r[4 + j] = (short)f2bf(v1[j]);
  }
  *((s16x8*)outp + id) = r;
}

// W [R][Ncols] f32  ->  WT [Ncols][R] bf16
__global__ void transpose_w_k(const float* __restrict__ W, u16* __restrict__ WT,
                              int Ncols, int R) {
  __shared__ u16 T_s[64 * 72];
  int c0 = blockIdx.x * 64, r0 = blockIdx.y * 64;
  int tid = threadIdx.x;
#pragma unroll
  for (int it = 0; it < 4; ++it) {
    int idx = it * 256 + tid;
    int r = idx >> 4, c4 = (idx & 15) * 4;
    fx4 v = *(const fx4*)(W + (u64)(r0 + r) * Ncols + c0 + c4);
#pragma unroll
    for (int j = 0; j < 4; ++j) T_s[(c4 + j) * 72 + r] = f2bf(v[j]);
  }
  __syncthreads();
#pragma unroll
  for (int it = 0; it < 2; ++it) {
    int idx = it * 256 + tid;
    int rc = idx >> 3, c8 = (idx & 7) * 8;
    s16x8 v = *(const s16x8*)(T_s + rc * 72 + c8);
    *(s16x8*)(WT + (u64)(c0 + rc) * R + r0 + c8) = v;
  }
}

// ---------- GEMM: A[M][K] bf16 @ B[N][K]^T bf16, 128x128 tile ----------
// EPI==0: C fp32 [M][N].
// EPI==1: fused RoPE epilogue, scatter to blocked Qp/Kp [bh][8][T][8]
//         (Q scaled by CF_) and Vp [bh][T/8][64][8].
template <int EPI>
__global__ __launch_bounds__(256, 2) void gemm_bt_k(
    const u16* __restrict__ A, const u16* __restrict__ B, float* __restrict__ C,
    u16* __restrict__ Qo, u16* __restrict__ Ko, u16* __restrict__ Vo,
    const float* __restrict__ ct, const float* __restrict__ st,
    int M, int N, int K) {
  __shared__ u16 As[128 * 32];
  __shared__ u16 Bs[128 * 32];
  int tid = threadIdx.x, lane = tid & 63, w = tid >> 6;
  int wm = w >> 1, wn = w & 1, l15 = lane & 15, l4 = lane >> 4;
  // XCD-bijective swizzle (nwg % 8 == 0 for all our grids)
  int nwg = gridDim.x * gridDim.y;
  int id = blockIdx.y * gridDim.x + blockIdx.x;
  int qq = nwg >> 3;
  id = (id & 7) * qq + (id >> 3);
  int m0 = (id / gridDim.x) * 128, n0 = (id % gridDim.x) * 128;
  fx4 acc[4][4] = {};
  int arow = tid >> 2, ac8 = (tid & 3) * 8;
  const u16* Ab = A + (u64)(m0 + arow) * K + ac8;
  const u16* Bb = B + (u64)(n0 + arow) * K + ac8;
  char* AsB = (char*)As + tid * 16;
  char* BsB = (char*)Bs + tid * 16;

  for (int k0 = 0; k0 < K; k0 += 32) {
    __syncthreads();
    gload16(Ab + k0, AsB);
    gload16(Ab + (u64)64 * K + k0, AsB + 4096);
    gload16(Bb + k0, BsB);
    gload16(Bb + (u64)64 * K + k0, BsB + 4096);
    __syncthreads();
    s16x8 a[4], b[4];
#pragma unroll
    for (int mi = 0; mi < 4; ++mi)
      a[mi] = *(const s16x8*)((const char*)As + (wm * 64 + mi * 16 + l15) * 64 + l4 * 16);
#pragma unroll
    for (int ni = 0; ni < 4; ++ni)
      b[ni] = *(const s16x8*)((const char*)Bs + (wn * 64 + ni * 16 + l15) * 64 + l4 * 16);
#pragma unroll
    for (int mi = 0; mi < 4; ++mi)
#pragma unroll
      for (int ni = 0; ni < 4; ++ni)
        acc[mi][ni] = mfma_16x16x32(a[mi], b[ni], acc[mi][ni]);
  }

  if (EPI == 0) {
#pragma unroll
    for (int mi = 0; mi < 4; ++mi)
#pragma unroll
      for (int ni = 0; ni < 4; ++ni)
#pragma unroll
        for (int r = 0; r < 4; ++r) {
          u64 row = (u64)(m0 + wm * 64 + mi * 16 + l4 * 4 + r);
          int col = n0 + wn * 64 + ni * 16 + l15;
          C[row * N + col] = acc[mi][ni][r];
        }
  } else {
#pragma unroll
    for (int mi = 0; mi < 4; ++mi)
#pragma unroll
      for (int r = 0; r < 4; ++r) {
        int row = m0 + wm * 64 + mi * 16 + l4 * 4 + r;
        int b2 = row >> 11, t = row & (T_ - 1);
#pragma unroll
        for (int ni = 0; ni < 2; ++ni) {
          int col = n0 + wn * 64 + ni * 16 + l15;
          int qi = col >> 10, h = (col >> 6) & 15, d = ni * 16 + l15;  // d in 0..31
          float lo = acc[mi][ni][r], hi = acc[mi][ni + 2][r];
          if (qi == 2) {
            u64 vbase =
                ((((u64)(b2 * H_ + h)) * (T_ / 8) + (t >> 3)) * HD_ + d) * 8 + (t & 7);
            Vo[vbase] = f2bf(lo);
            Vo[vbase + 32 * 8] = f2bf(hi);
          } else {
            float c = ct[t * 32 + d], s = st[t * 32 + d];
            float sc = (qi == 0) ? CF_ : 1.0f;
            u16* dst = (qi == 0) ? Qo : Ko;
            u64 base = ((((u64)(b2 * H_ + h)) * 8 + (d >> 3)) * T_ + t) * 8 + (d & 7);
            dst[base] = f2bf((lo * c - hi * s) * sc);
            dst[base + (u64)4 * T_ * 8] = f2bf((hi * c + lo * s) * sc);
          }
        }
      }
  }
}

// ---------- flash attention, swapped-QK^T, 1 wave/block, KV-split ----------
// Qp,Kp [bh][8 dblocks][T][8] bf16 (RoPE'd; Q pre-scaled by CF_)
// Vp [bh][T/8 kblocks][64 d][8 keys] bf16
// j < 32: direct write to Y.  j >= 32: 3 KV-chunks -> partials (Op, ML).

#define ATTN_LOAD(KC, VC, KVI)                                         \
  do {                                                                 \
    _Pragma("unroll")                                                  \
    for (int ks_ = 0; ks_ < 4; ++ks_)                                  \
      KC[ks_] = *(const s16x8*)(kp[ks_] + (u64)(KVI) * 256);           \
    const u16* vk_ = vpb + (u64)(KVI) * 2048;                          \
    VC[0] = *(const s16x8*)(vk_);                                      \
    VC[1] = *(const s16x8*)(vk_ + 256);                                \
    VC[2] = *(const s16x8*)(vk_ + 1024);                               \
    VC[3] = *(const s16x8*)(vk_ + 1280);                               \
  } while (0)

#define ATTN_BODY(KC, VC, KVI)                                                \
  do {                                                                        \
    fx16 s = {};                                                              \
    __builtin_amdgcn_s_setprio(1);                                            \
    _Pragma("unroll")                                                         \
    for (int ks_ = 0; ks_ < 4; ++ks_) s = mfma_32x32x16(KC[ks_], qf[ks_], s); \
    __builtin_amdgcn_s_setprio(0);                                            \
    if ((KVI) == j) {                                                         \
      _Pragma("unroll")                                                       \
      for (int r_ = 0; r_ < 16; ++r_) {                                       \
        int cr_ = (r_ & 3) + 8 * (r_ >> 2) + 4 * h;                           \
        s[r_] = (cr_ > ql) ? -1e30f : s[r_];                                  \
      }                                                                       \
    }                                                                         \
    float u0_ = max3f(s[0], s[1], s[2]);                                      \
    float u1_ = max3f(s[3], s[4], s[5]);                                      \
    float u2_ = max3f(s[6], s[7], s[8]);                                      \
    float u3_ = max3f(s[9], s[10], s[11]);                                    \
    float u4_ = max3f(s[12], s[13], s[14]);                                   \
    float v0_ = max3f(u0_, u1_, s[15]);                                       \
    float v1_ = max3f(u2_, u3_, u4_);                                         \
    float rowmax_ = xhalf_max(fmaxf(v0_, v1_));                               \
    if (!__all(rowmax_ <= m + 8.f)) {                                         \
      float mnew_ = fmaxf(m, rowmax_);                                        \
      float corr_ = exp2f(m - mnew_);                                         \
      l *= corr_;                                                             \
      oL *= corr_;                                                            \
      oH *= corr_;                                                            \
      m = mnew_;                                                              \
    }                                                                         \
    float p_[16];                                                             \
    _Pragma("unroll")                                                         \
    for (int r_ = 0; r_ < 16; ++r_) p_[r_] = exp2f(s[r_] - m);                \
    float a0_ = (p_[0] + p_[8]) + (p_[1] + p_[9]);                            \
    float a1_ = (p_[2] + p_[10]) + (p_[3] + p_[11]);                          \
    float a2_ = (p_[4] + p_[12]) + (p_[5] + p_[13]);                          \
    float a3_ = (p_[6] + p_[14]) + (p_[7] + p_[15]);                          \
    l += xhalf_sum((a0_ + a1_) + (a2_ + a3_));                                \
    u32 x0_ = cvtpk(p_[0], p_[1]), x1_ = cvtpk(p_[2], p_[3]);                 \
    u32 y0_ = cvtpk(p_[4], p_[5]), y1_ = cvtpk(p_[6], p_[7]);                 \
    plswap(x0_, y0_);                                                         \
    plswap(x1_, y1_);                                                         \
    u32x4 f0w_ = {x0_, x1_, y0_, y1_};                                        \
    u32 x2_ = cvtpk(p_[8], p_[9]), x3_ = cvtpk(p_[10], p_[11]);               \
    u32 y2_ = cvtpk(p_[12], p_[13]), y3_ = cvtpk(p_[14], p_[15]);             \
    plswap(x2_, y2_);                                                         \
    plswap(x3_, y3_);                                                         \
    u32x4 f1w_ = {x2_, x3_, y2_, y3_};                                        \
    s16x8 pf0_ = __builtin_bit_cast(s16x8, f0w_);                             \
    s16x8 pf1_ = __builtin_bit_cast(s16x8, f1w_);                             \
    __builtin_amdgcn_s_setprio(1);                                            \
    oL = mfma_32x32x16(VC[0], pf0_, oL);                                      \
    oH = mfma_32x32x16(VC[1], pf0_, oH);                                      \
    oL = mfma_32x32x16(VC[2], pf1_, oL);                                      \
    oH = mfma_32x32x16(VC[3], pf1_, oH);                                      \
    __builtin_amdgcn_s_setprio(0);                                            \
  } while (0)

__global__ __launch_bounds__(64, 4) void attn_fwd_k(
    const u16* __restrict__ Qp, const u16* __restrict__ Kp,
    const u16* __restrict__ Vp, u16* __restrict__ Y,
    u16* __restrict__ Op, float* __restrict__ ML) {
  int lane = threadIdx.x;
  int ql = lane & 31, h = lane >> 5;
  int b = blockIdx.x;            // 4096 blocks
  int bh = b & 31;
  int e = b >> 5;                // 0..127
  int j, kvlo, kvhi;
  if (e < 96) {                  // split tiles j=63..32, 3 chunks each
    int jj = e / 3, c = e - jj * 3;
    j = 63 - jj;
    int n = j + 1;
    kvlo = (c * n) / 3;
    kvhi = ((c + 1) * n) / 3;
  } else {                       // full tiles j=31..0
    j = 127 - e;
    kvlo = 0;
    kvhi = j + 1;
  }
  int q0 = j * 32;
  int b2 = bh >> 4, head = bh & 15;

  // Q fragments (B-operand): row=q=lane&31, k = h*8+i within each 16-d step
  s16x8 qf[4];
#pragma unroll
  for (int ks = 0; ks < 4; ++ks)
    qf[ks] = *(const s16x8*)(Qp + (((u64)bh * 8 + ks * 2 + h) * T_ + q0 + ql) * 8);

  const u16* kp[4];
#pragma unroll
  for (int ks = 0; ks < 4; ++ks)
    kp[ks] = Kp + (((u64)bh * 8 + ks * 2 + h) * T_ + ql) * 8;
  const u16* vpb = Vp + (((u64)bh * (T_ / 8) + h) * HD_ + ql) * 8;

  fx16 oL = {}, oH = {};
  float m = -1e30f, l = 0.f;

  if (kvlo < kvhi) {
    s16x8 kA[4], vA[4], kB[4], vB[4];
    ATTN_LOAD(kA, vA, kvlo);
    int kv = kvlo;
    for (; kv + 1 < kvhi; kv += 2) {
      ATTN_LOAD(kB, vB, kv + 1);
      ATTN_BODY(kA, vA, kv);
      if (kv + 2 < kvhi) ATTN_LOAD(kA, vA, kv + 2);
      ATTN_BODY(kB, vB, kv + 1);
    }
    if (kv < kvhi) ATTN_BODY(kA, vA, kv);
  }

  if (e >= 96) {
    // direct write: Y[b][t][head*64+d] = O/l
    float rl = 1.0f / l;
    int t = q0 + ql;
    u64 ybase = ((u64)(b2 * T_ + t)) * C_ + head * HD_;
#pragma unroll
    for (int g = 0; g < 4; ++g) {
      u32x2 s2;
      s2[0] = cvtpk(oL[4 * g] * rl, oL[4 * g + 1] * rl);
      s2[1] = cvtpk(oL[4 * g + 2] * rl, oL[4 * g + 3] * rl);
      *(u32x2*)(Y + ybase + g * 8 + h * 4) = s2;
      u32x2 s3;
      s3[0] = cvtpk(oH[4 * g] * rl, oH[4 * g + 1] * rl);
      s3[1] = cvtpk(oH[4 * g + 2] * rl, oH[4 * g + 3] * rl);
      *(u32x2*)(Y + ybase + 32 + g * 8 + h * 4) = s3;
    }
  } else {
    // partial write: Op[cidx][q][d] (raw O, bf16), ML[cidx][q] = (m, l)
    int cidx = bh * 96 + e;
    u64 ob = ((u64)(cidx * 32 + ql)) * 64;
#pragma unroll
    for (int g = 0; g < 4; ++g) {
      u32x2 s2;
      s2[0] = cvtpk(oL[4 * g], oL[4 * g + 1]);
      s2[1] = cvtpk(oL[4 * g + 2], oL[4 * g + 3]);
      *(u32x2*)(Op + ob + g * 8 + h * 4) = s2;
      u32x2 s3;
      s3[0] = cvtpk(oH[4 * g], oH[4 * g + 1]);
      s3[1] = cvtpk(oH[4 * g + 2], oH[4 * g + 3]);
      *(u32x2*)(Op + ob + 32 + g * 8 + h * 4) = s3;
    }
    if (h == 0) {
      float* mp = ML + ((u64)(cidx * 32 + ql)) * 2;
      mp[0] = m;
      mp[1] = l;
    }
  }
}

// ---------- combine: merge 3 partials per split tile ----------
__global__ __launch_bounds__(256) void attn_combine_k(
    const u16* __restrict__ Op, const float* __restrict__ ML,
    u16* __restrict__ Y) {
  int tid = threadIdx.x;
  int tt = blockIdx.x * 4 + (tid >> 6);   // 0..1023 split tiles
  int g = tid & 63;
  int qs = g >> 3, dg = g & 7;
  int bh = tt >> 5, jj = tt & 31;
  int j = 63 - jj;
  int b2 = bh >> 4, head = bh & 15;
  int c0 = bh * 96 + jj * 3;
#pragma unroll
  for (int r4 = 0; r4 < 4; ++r4) {
    int q = r4 * 8 + qs;
    const float* ml0 = ML + ((u64)(c0 * 32 + q)) * 2;
    float m1 = ml0[0], l1 = ml0[1];
    float m2 = ml0[64], l2 = ml0[65];
    float m3 = ml0[128], l3 = ml0[129];
    float mo = max3f(m1, m2, m3);
    float w1 = exp2f(m1 - mo), w2 = exp2f(m2 - mo), w3 = exp2f(m3 - mo);
    float rl = 1.0f / (l1 * w1 + l2 * w2 + l3 * w3);
    w1 *= rl;
    w2 *= rl;
    w3 *= rl;
    const u16* ob = Op + ((u64)(c0 * 32 + q)) * 64 + dg * 8;
    s16x8 o1 = *(const s16x8*)(ob);
    s16x8 o2 = *(const s16x8*)(ob + 2048);
    s16x8 o3 = *(const s16x8*)(ob + 4096);
    u32x4 outw;
#pragma unroll
    for (int p2 = 0; p2 < 4; ++p2) {
      float lo = bf2f((u16)o1[2 * p2]) * w1 + bf2f((u16)o2[2 * p2]) * w2 +
                 bf2f((u16)o3[2 * p2]) * w3;
      float hi = bf2f((u16)o1[2 * p2 + 1]) * w1 + bf2f((u16)o2[2 * p2 + 1]) * w2 +
                 bf2f((u16)o3[2 * p2 + 1]) * w3;
      outw[p2] = cvtpk(lo, hi);
    }
    int t = j * 32 + q;
    *(u32x4*)(Y + ((u64)(b2 * T_ + t)) * C_ + head * HD_ + dg * 8) = outw;
  }
}

// ---------- launcher ----------
extern "C" void kernel_launch(void* const* d_in, const int* in_sizes, int n_in,
                              void* d_out, int out_size, void* d_ws, size_t ws_size,
                              hipStream_t stream) {
  (void)in_sizes; (void)n_in; (void)out_size; (void)ws_size;
  const float* x = (const float*)d_in[0];
  const float* w_attn = (const float*)d_in[1];
  const float* w_proj = (const float*)d_in[2];
  float* out = (float*)d_out;

  u16* xb = (u16*)d_ws;                       // [4096][1024] bf16
  u16* waT = xb + (u64)M_ * C_;               // [3072][1024]
  u16* wpT = waT + (u64)3 * C_ * C_;          // [1024][1024]
  u16* Qp = wpT + (u64)C_ * C_;               // [32][8][2048][8]
  u16* Kp = Qp + (u64)BH_ * T_ * HD_;
  u16* Vp = Kp + (u64)BH_ * T_ * HD_;         // [32][256][64][8]
  float* ct = (float*)(Vp + (u64)BH_ * T_ * HD_);
  float* st = ct + T_ * 32;
  u16* Yb = (u16*)(st + T_ * 32);             // fresh [4096][1024] bf16
  float* ML = (float*)(Yb + (u64)M_ * C_);    // [3072][32][2] f32
  u16* Op = xb;                                // partials overlay xb+waT (12MB)

  rope_table_k<<<256, 256, 0, stream>>>(ct, st);
  cvt_f32_bf16_k<<<(M_ * C_ / 8) / 256, 256, 0, stream>>>(x, xb);
  transpose_w_k<<<dim3(48, 16), 256, 0, stream>>>(w_attn, waT, 3 * C_, C_);
  transpose_w_k<<<dim3(16, 16), 256, 0, stream>>>(w_proj, wpT, C_, C_);

  gemm_bt_k<1><<<dim3(24, 32), 256, 0, stream>>>(xb, waT, nullptr, Qp, Kp, Vp,
                                                 ct, st, M_, 3 * C_, C_);

  attn_fwd_k<<<4096, 64, 0, stream>>>(Qp, Kp, Vp, Yb, Op, ML);
  attn_combine_k<<<256, 256, 0, stream>>>(Op, ML, Yb);

  gemm_bt_k<0><<<dim3(8, 32), 256, 0, stream>>>(Yb, wpT, out, nullptr, nullptr,
                                                nullptr, nullptr, nullptr,
                                                M_, C_, C_);
}

// Round 5
// 132.468 us; speedup vs baseline: 1.3251x; 1.3251x over previous
//
#include <hip/hip_runtime.h>

typedef unsigned short u16;
typedef unsigned int u32;
typedef unsigned long long u64;
typedef __attribute__((ext_vector_type(8))) short s16x8;
typedef __attribute__((ext_vector_type(8))) __bf16 bf16x8;
typedef __attribute__((ext_vector_type(4))) float fx4;
typedef __attribute__((ext_vector_type(16))) float fx16;
typedef __attribute__((ext_vector_type(2))) u32 u32x2;
typedef __attribute__((ext_vector_type(4))) u32 u32x4;

// ---------- helpers ----------
__device__ __forceinline__ fx4 mfma_16x16x32(s16x8 a, s16x8 b, fx4 c) {
  return __builtin_amdgcn_mfma_f32_16x16x32_bf16(
      __builtin_bit_cast(bf16x8, a), __builtin_bit_cast(bf16x8, b), c, 0, 0, 0);
}
__device__ __forceinline__ fx16 mfma_32x32x16(s16x8 a, s16x8 b, fx16 c) {
  return __builtin_amdgcn_mfma_f32_32x32x16_bf16(
      __builtin_bit_cast(bf16x8, a), __builtin_bit_cast(bf16x8, b), c, 0, 0, 0);
}

__device__ __forceinline__ u16 f2bf(float f) {
  u32 u = __builtin_bit_cast(u32, f);
  u32 r = u + 0x7fffu + ((u >> 16) & 1u);
  return (u16)(r >> 16);
}
__device__ __forceinline__ float bf2f(u16 h) {
  u32 u = ((u32)h) << 16;
  return __builtin_bit_cast(float, u);
}

__device__ __forceinline__ u32 cvtpk(float lo, float hi) {
  u32 r;
  asm("v_cvt_pk_bf16_f32 %0, %1, %2" : "=v"(r) : "v"(lo), "v"(hi));
  return r;
}

__device__ __forceinline__ float max3f(float a, float b, float c) {
  float r;
  asm("v_max3_f32 %0, %1, %2, %3" : "=v"(r) : "v"(a), "v"(b), "v"(c));
  return r;
}

__device__ __forceinline__ void plswap(u32& x, u32& y) {
  typedef __attribute__((ext_vector_type(2))) unsigned int uix2;
  uix2 r = __builtin_amdgcn_permlane32_swap(x, y, false, false);
  x = r[0];
  y = r[1];
}

__device__ __forceinline__ float xhalf_max(float v) {
  u32 a = __builtin_bit_cast(u32, v), b = a;
  plswap(a, b);
  return fmaxf(__builtin_bit_cast(float, a), __builtin_bit_cast(float, b));
}
__device__ __forceinline__ float xhalf_sum(float v) {
  u32 a = __builtin_bit_cast(u32, v), b = a;
  plswap(a, b);
  return __builtin_bit_cast(float, a) + __builtin_bit_cast(float, b);
}

__device__ __forceinline__ void gload16(const void* g, void* l) {
  __builtin_amdgcn_global_load_lds(
      (const __attribute__((address_space(1))) u32*)g,
      (__attribute__((address_space(3))) u32*)l, 16, 0, 0);
}

// ---------- constants ----------
#define B_ 2
#define T_ 2048
#define C_ 1024
#define H_ 16
#define HD_ 64
#define BH_ 32
#define M_ 4096   // B*T
// (1/sqrt(64)) * log2(e), folded into Q at GEMM1 epilogue (fused RoPE)
#define CF_ 0.18033688011112042f

// ---------- prep kernels ----------
__global__ void rope_table_k(float* __restrict__ ct, float* __restrict__ st) {
  int id = blockIdx.x * 256 + threadIdx.x;  // 65536 = T*32
  int t = id >> 5, i = id & 31;
  float f = exp2f(-(float)i * (13.287712379549449f / 32.0f));
  float a = (float)t * f;
  float s, c;
  sincosf(a, &s, &c);
  ct[id] = c;
  st[id] = s;
}

__global__ void cvt_f32_bf16_k(const float* __restrict__ in, u16* __restrict__ outp) {
  int id = blockIdx.x * 256 + threadIdx.x;
  const fx4* p = (const fx4*)(in + (u64)id * 8);
  fx4 v0 = p[0], v1 = p[1];
  s16x8 r;
#pragma unroll
  for (int j = 0; j < 4; ++j) {
    r[j] = (short)f2bf(v0[j]);
    r[4 + j] = (short)f2bf(v1[j]);
  }
  *((s16x8*)outp + id) = r;
}

// W [R][Ncols] f32  ->  WT [Ncols][R] bf16
__global__ void transpose_w_k(const float* __restrict__ W, u16* __restrict__ WT,
                              int Ncols, int R) {
  __shared__ u16 T_s[64 * 72];
  int c0 = blockIdx.x * 64, r0 = blockIdx.y * 64;
  int tid = threadIdx.x;
#pragma unroll
  for (int it = 0; it < 4; ++it) {
    int idx = it * 256 + tid;
    int r = idx >> 4, c4 = (idx & 15) * 4;
    fx4 v = *(const fx4*)(W + (u64)(r0 + r) * Ncols + c0 + c4);
#pragma unroll
    for (int j = 0; j < 4; ++j) T_s[(c4 + j) * 72 + r] = f2bf(v[j]);
  }
  __syncthreads();
#pragma unroll
  for (int it = 0; it < 2; ++it) {
    int idx = it * 256 + tid;
    int rc = idx >> 3, c8 = (idx & 7) * 8;
    s16x8 v = *(const s16x8*)(T_s + rc * 72 + c8);
    *(s16x8*)(WT + (u64)(c0 + rc) * R + r0 + c8) = v;
  }
}

// ---------- GEMM: A[M][K] bf16 @ B[N][K]^T bf16, 128x128 tile ----------
// EPI==0: C fp32 [M][N].
// EPI==1: fused RoPE epilogue, scatter to blocked Qp/Kp [bh][8][T][8]
//         (Q scaled by CF_) and Vp [bh][T/8][64][8].
template <int EPI>
__global__ __launch_bounds__(256, 2) void gemm_bt_k(
    const u16* __restrict__ A, const u16* __restrict__ B, float* __restrict__ C,
    u16* __restrict__ Qo, u16* __restrict__ Ko, u16* __restrict__ Vo,
    const float* __restrict__ ct, const float* __restrict__ st,
    int M, int N, int K) {
  __shared__ u16 As[128 * 32];
  __shared__ u16 Bs[128 * 32];
  int tid = threadIdx.x, lane = tid & 63, w = tid >> 6;
  int wm = w >> 1, wn = w & 1, l15 = lane & 15, l4 = lane >> 4;
  // XCD-bijective swizzle (nwg % 8 == 0 for all our grids)
  int nwg = gridDim.x * gridDim.y;
  int id = blockIdx.y * gridDim.x + blockIdx.x;
  int qq = nwg >> 3;
  id = (id & 7) * qq + (id >> 3);
  int m0 = (id / gridDim.x) * 128, n0 = (id % gridDim.x) * 128;
  fx4 acc[4][4] = {};
  int arow = tid >> 2, ac8 = (tid & 3) * 8;
  const u16* Ab = A + (u64)(m0 + arow) * K + ac8;
  const u16* Bb = B + (u64)(n0 + arow) * K + ac8;
  char* AsB = (char*)As + tid * 16;
  char* BsB = (char*)Bs + tid * 16;

  for (int k0 = 0; k0 < K; k0 += 32) {
    __syncthreads();
    gload16(Ab + k0, AsB);
    gload16(Ab + (u64)64 * K + k0, AsB + 4096);
    gload16(Bb + k0, BsB);
    gload16(Bb + (u64)64 * K + k0, BsB + 4096);
    __syncthreads();
    s16x8 a[4], b[4];
#pragma unroll
    for (int mi = 0; mi < 4; ++mi)
      a[mi] = *(const s16x8*)((const char*)As + (wm * 64 + mi * 16 + l15) * 64 + l4 * 16);
#pragma unroll
    for (int ni = 0; ni < 4; ++ni)
      b[ni] = *(const s16x8*)((const char*)Bs + (wn * 64 + ni * 16 + l15) * 64 + l4 * 16);
#pragma unroll
    for (int mi = 0; mi < 4; ++mi)
#pragma unroll
      for (int ni = 0; ni < 4; ++ni)
        acc[mi][ni] = mfma_16x16x32(a[mi], b[ni], acc[mi][ni]);
  }

  if (EPI == 0) {
#pragma unroll
    for (int mi = 0; mi < 4; ++mi)
#pragma unroll
      for (int ni = 0; ni < 4; ++ni)
#pragma unroll
        for (int r = 0; r < 4; ++r) {
          u64 row = (u64)(m0 + wm * 64 + mi * 16 + l4 * 4 + r);
          int col = n0 + wn * 64 + ni * 16 + l15;
          C[row * N + col] = acc[mi][ni][r];
        }
  } else {
#pragma unroll
    for (int mi = 0; mi < 4; ++mi)
#pragma unroll
      for (int r = 0; r < 4; ++r) {
        int row = m0 + wm * 64 + mi * 16 + l4 * 4 + r;
        int b2 = row >> 11, t = row & (T_ - 1);
#pragma unroll
        for (int ni = 0; ni < 2; ++ni) {
          int col = n0 + wn * 64 + ni * 16 + l15;
          int qi = col >> 10, h = (col >> 6) & 15, d = ni * 16 + l15;  // d in 0..31
          float lo = acc[mi][ni][r], hi = acc[mi][ni + 2][r];
          if (qi == 2) {
            u64 vbase =
                ((((u64)(b2 * H_ + h)) * (T_ / 8) + (t >> 3)) * HD_ + d) * 8 + (t & 7);
            Vo[vbase] = f2bf(lo);
            Vo[vbase + 32 * 8] = f2bf(hi);
          } else {
            float c = ct[t * 32 + d], s = st[t * 32 + d];
            float sc = (qi == 0) ? CF_ : 1.0f;
            u16* dst = (qi == 0) ? Qo : Ko;
            u64 base = ((((u64)(b2 * H_ + h)) * 8 + (d >> 3)) * T_ + t) * 8 + (d & 7);
            dst[base] = f2bf((lo * c - hi * s) * sc);
            dst[base + (u64)4 * T_ * 8] = f2bf((hi * c + lo * s) * sc);
          }
        }
      }
  }
}

// ---------- flash attention: swapped-QK^T, 1 wave/block, two in-register
// KV chains (A: [0,nA), B: [nA,n)) merged in-register at the end ----------
// Qp,Kp [bh][8 dblocks][T][8] bf16 (RoPE'd; Q pre-scaled by CF_)
// Vp [bh][T/8 kblocks][64 d][8 keys] bf16
// Y [B][T][C] bf16

#define LOADK(KC, KVI)                                                 \
  do {                                                                 \
    _Pragma("unroll")                                                  \
    for (int ks_ = 0; ks_ < 4; ++ks_)                                  \
      KC[ks_] = *(const s16x8*)(kp[ks_] + (u64)(KVI) * 256);           \
  } while (0)

#define LOADV(VC, KVI)                                                 \
  do {                                                                 \
    const u16* vk_ = vpb + (u64)(KVI) * 2048;                          \
    VC[0] = *(const s16x8*)(vk_);                                      \
    VC[1] = *(const s16x8*)(vk_ + 256);                                \
    VC[2] = *(const s16x8*)(vk_ + 1024);                               \
    VC[3] = *(const s16x8*)(vk_ + 1280);                               \
  } while (0)

#define QKT(SC, KC)                                                          \
  do {                                                                       \
    SC = (fx16){};                                                           \
    __builtin_amdgcn_s_setprio(1);                                           \
    _Pragma("unroll")                                                        \
    for (int ks_ = 0; ks_ < 4; ++ks_) SC = mfma_32x32x16(KC[ks_], qf[ks_], SC); \
    __builtin_amdgcn_s_setprio(0);                                           \
  } while (0)

#define SMPV(SC, VC, KVI, M0, L0, OL, OH)                                     \
  do {                                                                        \
    if ((KVI) == j) {                                                         \
      _Pragma("unroll")                                                       \
      for (int r_ = 0; r_ < 16; ++r_) {                                       \
        int cr_ = (r_ & 3) + 8 * (r_ >> 2) + 4 * h;                           \
        SC[r_] = (cr_ > ql) ? -1e30f : SC[r_];                                \
      }                                                                       \
    }                                                                         \
    float u0_ = max3f(SC[0], SC[1], SC[2]);                                   \
    float u1_ = max3f(SC[3], SC[4], SC[5]);                                   \
    float u2_ = max3f(SC[6], SC[7], SC[8]);                                   \
    float u3_ = max3f(SC[9], SC[10], SC[11]);                                 \
    float u4_ = max3f(SC[12], SC[13], SC[14]);                                \
    float v0_ = max3f(u0_, u1_, SC[15]);                                      \
    float v1_ = max3f(u2_, u3_, u4_);                                         \
    float rowmax_ = xhalf_max(fmaxf(v0_, v1_));                               \
    if (!__all(rowmax_ <= M0 + 8.f)) {                                        \
      float mnew_ = fmaxf(M0, rowmax_);                                       \
      float corr_ = exp2f(M0 - mnew_);                                        \
      L0 *= corr_;                                                            \
      OL *= corr_;                                                            \
      OH *= corr_;                                                            \
      M0 = mnew_;                                                             \
    }                                                                         \
    float p_[16];                                                             \
    _Pragma("unroll")                                                         \
    for (int r_ = 0; r_ < 16; ++r_) p_[r_] = exp2f(SC[r_] - M0);              \
    float a0_ = (p_[0] + p_[8]) + (p_[1] + p_[9]);                            \
    float a1_ = (p_[2] + p_[10]) + (p_[3] + p_[11]);                          \
    float a2_ = (p_[4] + p_[12]) + (p_[5] + p_[13]);                          \
    float a3_ = (p_[6] + p_[14]) + (p_[7] + p_[15]);                          \
    L0 += xhalf_sum((a0_ + a1_) + (a2_ + a3_));                               \
    u32 x0_ = cvtpk(p_[0], p_[1]), x1_ = cvtpk(p_[2], p_[3]);                 \
    u32 y0_ = cvtpk(p_[4], p_[5]), y1_ = cvtpk(p_[6], p_[7]);                 \
    plswap(x0_, y0_);                                                         \
    plswap(x1_, y1_);                                                         \
    u32x4 f0w_ = {x0_, x1_, y0_, y1_};                                        \
    u32 x2_ = cvtpk(p_[8], p_[9]), x3_ = cvtpk(p_[10], p_[11]);               \
    u32 y2_ = cvtpk(p_[12], p_[13]), y3_ = cvtpk(p_[14], p_[15]);             \
    plswap(x2_, y2_);                                                         \
    plswap(x3_, y3_);                                                         \
    u32x4 f1w_ = {x2_, x3_, y2_, y3_};                                        \
    s16x8 pf0_ = __builtin_bit_cast(s16x8, f0w_);                             \
    s16x8 pf1_ = __builtin_bit_cast(s16x8, f1w_);                             \
    __builtin_amdgcn_s_setprio(1);                                            \
    OL = mfma_32x32x16(VC[0], pf0_, OL);                                      \
    OH = mfma_32x32x16(VC[1], pf0_, OH);                                      \
    OL = mfma_32x32x16(VC[2], pf1_, OL);                                      \
    OH = mfma_32x32x16(VC[3], pf1_, OH);                                      \
    __builtin_amdgcn_s_setprio(0);                                            \
  } while (0)

__global__ __launch_bounds__(64, 2) void attn_fwd_k(
    const u16* __restrict__ Qp, const u16* __restrict__ Kp,
    const u16* __restrict__ Vp, u16* __restrict__ Y) {
  int lane = threadIdx.x;
  int ql = lane & 31, h = lane >> 5;
  int bh = blockIdx.x & 31;
  int j = 63 - (blockIdx.x >> 5);   // long tiles first
  int q0 = j * 32;
  int b2 = bh >> 4, head = bh & 15;

  // Q fragments (B-operand): row=q=lane&31, k = h*8+i within each 16-d step
  s16x8 qf[4];
#pragma unroll
  for (int ks = 0; ks < 4; ++ks)
    qf[ks] = *(const s16x8*)(Qp + (((u64)bh * 8 + ks * 2 + h) * T_ + q0 + ql) * 8);

  const u16* kp[4];
#pragma unroll
  for (int ks = 0; ks < 4; ++ks)
    kp[ks] = Kp + (((u64)bh * 8 + ks * 2 + h) * T_ + ql) * 8;
  const u16* vpb = Vp + (((u64)bh * (T_ / 8) + h) * HD_ + ql) * 8;

  int n = j + 1;
  int nB = n >> 1, nA = n - nB;   // A: [0,nA), B: [nA,n)

  fx16 oLA = {}, oHA = {}, oLB = {}, oHB = {};
  float mA = -1e30f, lA = 0.f, mB = -1e30f, lB = 0.f;

  s16x8 kA[4], vA[4], kB[4], vB[4];
  LOADK(kA, 0);
  LOADV(vA, 0);
  if (nB > 0) {
    LOADK(kB, nA);
    LOADV(vB, nA);
  }

  for (int i = 0; i < nB; ++i) {
    fx16 sA, sB;
    QKT(sA, kA);
    if (i + 1 < nA) LOADK(kA, i + 1);
    QKT(sB, kB);
    if (i + 1 < nB) LOADK(kB, nA + i + 1);
    SMPV(sA, vA, i, mA, lA, oLA, oHA);
    if (i + 1 < nA) LOADV(vA, i + 1);
    SMPV(sB, vB, nA + i, mB, lB, oLB, oHB);
    if (i + 1 < nB) LOADV(vB, nA + i + 1);
  }
  if (nA > nB) {
    fx16 sA;
    QKT(sA, kA);
    SMPV(sA, vA, nA - 1, mA, lA, oLA, oHA);
  }

  // ---- merge chains + epilogue: Y[b][t][head*64+d] = O/l
  float mo = fmaxf(mA, mB);
  float sfA = exp2f(mA - mo), sfB = exp2f(mB - mo);
  float rl = 1.0f / (lA * sfA + lB * sfB);
  float cA = sfA * rl, cB = sfB * rl;
  int t = q0 + ql;
  u64 ybase = ((u64)(b2 * T_ + t)) * C_ + head * HD_;
#pragma unroll
  for (int g = 0; g < 4; ++g) {
    u32x2 s2;
    s2[0] = cvtpk(oLA[4 * g] * cA + oLB[4 * g] * cB,
                  oLA[4 * g + 1] * cA + oLB[4 * g + 1] * cB);
    s2[1] = cvtpk(oLA[4 * g + 2] * cA + oLB[4 * g + 2] * cB,
                  oLA[4 * g + 3] * cA + oLB[4 * g + 3] * cB);
    *(u32x2*)(Y + ybase + g * 8 + h * 4) = s2;
    u32x2 s3;
    s3[0] = cvtpk(oHA[4 * g] * cA + oHB[4 * g] * cB,
                  oHA[4 * g + 1] * cA + oHB[4 * g + 1] * cB);
    s3[1] = cvtpk(oHA[4 * g + 2] * cA + oHB[4 * g + 2] * cB,
                  oHA[4 * g + 3] * cA + oHB[4 * g + 3] * cB);
    *(u32x2*)(Y + ybase + 32 + g * 8 + h * 4) = s3;
  }
}

// ---------- launcher ----------
extern "C" void kernel_launch(void* const* d_in, const int* in_sizes, int n_in,
                              void* d_out, int out_size, void* d_ws, size_t ws_size,
                              hipStream_t stream) {
  (void)in_sizes; (void)n_in; (void)out_size; (void)ws_size;
  const float* x = (const float*)d_in[0];
  const float* w_attn = (const float*)d_in[1];
  const float* w_proj = (const float*)d_in[2];
  float* out = (float*)d_out;

  u16* xb = (u16*)d_ws;                       // [4096][1024] bf16 (reused as Y)
  u16* waT = xb + (u64)M_ * C_;               // [3072][1024]
  u16* wpT = waT + (u64)3 * C_ * C_;          // [1024][1024]
  u16* Qp = wpT + (u64)C_ * C_;               // [32][8][2048][8]
  u16* Kp = Qp + (u64)BH_ * T_ * HD_;
  u16* Vp = Kp + (u64)BH_ * T_ * HD_;         // [32][256][64][8]
  float* ct = (float*)(Vp + (u64)BH_ * T_ * HD_);
  float* st = ct + T_ * 32;
  u16* yb = xb;                               // reuse xb after GEMM1

  rope_table_k<<<256, 256, 0, stream>>>(ct, st);
  cvt_f32_bf16_k<<<(M_ * C_ / 8) / 256, 256, 0, stream>>>(x, xb);
  transpose_w_k<<<dim3(48, 16), 256, 0, stream>>>(w_attn, waT, 3 * C_, C_);
  transpose_w_k<<<dim3(16, 16), 256, 0, stream>>>(w_proj, wpT, C_, C_);

  gemm_bt_k<1><<<dim3(24, 32), 256, 0, stream>>>(xb, waT, nullptr, Qp, Kp, Vp,
                                                 ct, st, M_, 3 * C_, C_);

  attn_fwd_k<<<2048, 64, 0, stream>>>(Qp, Kp, Vp, yb);

  gemm_bt_k<0><<<dim3(8, 32), 256, 0, stream>>>(yb, wpT, out, nullptr, nullptr,
                                                nullptr, nullptr, nullptr,
                                                M_, C_, C_);
}